// Round 3
// baseline (425.330 us; speedup 1.0000x reference)
//
#include <hip/hip_runtime.h>
#include <hip/hip_bf16.h>

#define EPS 1e-5f
#define INV15 (1.0f/15.0f)

#define NB 32
#define CIN 64
#define HID 384
#define HH 56
#define HW 3136      // 56*56
#define PPI 1568     // pixel pairs per image
#define WB 28        // packed bytes per row

// ws layout (bytes)
#define OFF_W1F 0
#define OFF_B1F 98304
#define OFF_W2F 99840
#define OFF_B2F 113664
#define OFF_W3F 115200
#define OFF_B3F 213504
#define OFF_MAX 213760
#define OFF_H1P (1u<<20)
#define H1P_BYTES (NB*HID*PPI)      // 19267584
#define OFF_H2P (OFF_H1P + H1P_BYTES)

__global__ __launch_bounds__(256) void prep_max(
    const float* __restrict__ w1, const float* __restrict__ w2,
    const float* __restrict__ w3, float* __restrict__ maxout) {
  __shared__ float red[256];
  int t = threadIdx.x;
  int b = blockIdx.x;
  const float* src = (b == 0) ? w1 : (b == 1) ? w2 : w3;
  int n = (b == 1) ? HID * 9 : HID * CIN;
  float m = 0.f;
  for (int i = t; i < n; i += 256)
    m = fmaxf(m, fabsf(tanhf(src[i])));
  red[t] = m; __syncthreads();
  for (int s = 128; s > 0; s >>= 1) {
    if (t < s) red[t] = fmaxf(red[t], red[t + s]);
    __syncthreads();
  }
  if (t == 0) maxout[b] = red[0];
}

__global__ __launch_bounds__(256) void prep_quant(
    const float* __restrict__ w1, const float* __restrict__ w2,
    const float* __restrict__ w3,
    const float* __restrict__ g1, const float* __restrict__ b1,
    const float* __restrict__ m1, const float* __restrict__ v1,
    const float* __restrict__ g2, const float* __restrict__ b2,
    const float* __restrict__ m2, const float* __restrict__ v2,
    const float* __restrict__ g3, const float* __restrict__ b3,
    const float* __restrict__ m3, const float* __restrict__ v3,
    const float* __restrict__ maxv,
    float* __restrict__ W1f, float* __restrict__ B1f,
    float* __restrict__ W2f, float* __restrict__ B2f,
    float* __restrict__ W3f, float* __restrict__ B3f) {
  int idx = blockIdx.x * 256 + threadIdx.x;
  if (idx < 24576) {                      // w1: [384][64]
    int o = idx >> 6;
    float s = g1[o] / sqrtf(v1[o] + EPS);
    float t = tanhf(w1[idx]);
    float q = 2.f * (rintf((t / (2.f * maxv[0]) + 0.5f) * 15.f) * INV15) - 1.f;
    W1f[idx] = q * s;
  } else if (idx < 28032) {               // w2: [384][9]
    int j = idx - 24576; int o = j / 9;
    float s = g2[o] / sqrtf(v2[o] + EPS);
    float t = tanhf(w2[j]);
    float q = 2.f * (rintf((t / (2.f * maxv[1]) + 0.5f) * 15.f) * INV15) - 1.f;
    W2f[j] = q * s;
  } else if (idx < 52608) {               // w3: [64][384]
    int j = idx - 28032; int o = j / 384;
    float s = g3[o] / sqrtf(v3[o] + EPS);
    float t = tanhf(w3[j]);
    float q = 2.f * (rintf((t / (2.f * maxv[2]) + 0.5f) * 15.f) * INV15) - 1.f;
    W3f[j] = q * s;
  } else if (idx < 52992) {
    int o = idx - 52608;
    float s = g1[o] / sqrtf(v1[o] + EPS);
    B1f[o] = b1[o] - m1[o] * s;
  } else if (idx < 53376) {
    int o = idx - 52992;
    float s = g2[o] / sqrtf(v2[o] + EPS);
    B2f[o] = b2[o] - m2[o] * s;
  } else if (idx < 53440) {
    int o = idx - 53376;
    float s = g3[o] / sqrtf(v3[o] + EPS);
    B3f[o] = b3[o] - m3[o] * s;
  }
}

// conv1 1x1 (64->384) + bn + relu + act_quant -> packed nibbles
__global__ __launch_bounds__(256) void k1(
    const float* __restrict__ x, const float* __restrict__ W1f,
    const float* __restrict__ B1f, unsigned char* __restrict__ h1p) {
  __shared__ float sW[32 * 64];
  __shared__ float sB[32];
  int tid = threadIdx.x;
  int o0 = blockIdx.y * 32;
  const float4* src4 = (const float4*)(W1f + o0 * 64);
  float4* dst4 = (float4*)sW;
  for (int i = tid; i < 512; i += 256) dst4[i] = src4[i];
  if (tid < 32) sB[tid] = B1f[o0 + tid];
  __syncthreads();

  int pairid = blockIdx.x * 256 + tid;
  int n = pairid / PPI;
  int pp = pairid - n * PPI;
  const float* xb = x + (size_t)n * CIN * HW + 2 * pp;

  float acc0[32], acc1[32];
  #pragma unroll
  for (int o = 0; o < 32; o++) { acc0[o] = sB[o]; acc1[o] = sB[o]; }

  for (int ct = 0; ct < 4; ct++) {
    float x0[16], x1[16];
    #pragma unroll
    for (int c = 0; c < 16; c++) {
      float2 xv = *(const float2*)(xb + (size_t)(ct * 16 + c) * HW);
      x0[c] = xv.x; x1[c] = xv.y;
    }
    #pragma unroll
    for (int o = 0; o < 32; o++) {
      const float* wr = &sW[o * 64 + ct * 16];
      #pragma unroll
      for (int c = 0; c < 16; c++) { float w = wr[c]; acc0[o] += w * x0[c]; acc1[o] += w * x1[c]; }
    }
  }
  unsigned char* dst = h1p + (size_t)(n * HID + o0) * PPI + pp;
  #pragma unroll
  for (int o = 0; o < 32; o++) {
    float a0 = fminf(fmaxf(acc0[o], 0.f), 1.f);
    float a1 = fminf(fmaxf(acc1[o], 0.f), 1.f);
    int q0 = (int)rintf(a0 * 15.f);
    int q1 = (int)rintf(a1 * 15.f);
    dst[(size_t)o * PPI] = (unsigned char)(q0 | (q1 << 4));
  }
}

// depthwise 3x3 + bn + relu + act_quant on packed nibbles
__global__ __launch_bounds__(256) void k2(
    const unsigned char* __restrict__ h1p, const float* __restrict__ W2f,
    const float* __restrict__ B2f, unsigned char* __restrict__ h2p) {
  int t = blockIdx.x * 256 + threadIdx.x;     // over NB*HID*PPI
  int pp = t % PPI;
  int rest = t / PPI;                         // n*HID + c
  int c = rest % HID;
  int wb = pp % WB;
  int h = pp / WB;
  const float* w = W2f + c * 9;
  float wreg[9];
  #pragma unroll
  for (int i = 0; i < 9; i++) wreg[i] = w[i];
  const unsigned char* base = h1p + (size_t)rest * PPI;
  float acc0 = B2f[c], acc1 = acc0;
  #pragma unroll
  for (int kh = 0; kh < 3; kh++) {
    int r = h - 1 + kh;
    if (r < 0 || r >= HH) continue;
    const unsigned char* row = base + r * WB;
    unsigned int bm = row[wb];
    unsigned int bl = (wb > 0) ? (unsigned int)row[wb - 1] : 0u;
    unsigned int br = (wb < WB - 1) ? (unsigned int)row[wb + 1] : 0u;
    float vm1 = (float)(bl >> 4) * INV15;
    float v0  = (float)(bm & 15u) * INV15;
    float v1  = (float)(bm >> 4) * INV15;
    float v2  = (float)(br & 15u) * INV15;
    acc0 += wreg[kh * 3 + 0] * vm1 + wreg[kh * 3 + 1] * v0 + wreg[kh * 3 + 2] * v1;
    acc1 += wreg[kh * 3 + 0] * v0  + wreg[kh * 3 + 1] * v1 + wreg[kh * 3 + 2] * v2;
  }
  float a0 = fminf(fmaxf(acc0, 0.f), 1.f);
  float a1 = fminf(fmaxf(acc1, 0.f), 1.f);
  int q0 = (int)rintf(a0 * 15.f);
  int q1 = (int)rintf(a1 * 15.f);
  h2p[(size_t)rest * PPI + pp] = (unsigned char)(q0 | (q1 << 4));
}

// conv3 1x1 (384->64) + bn + act_quant + residual -> fp32 out
__global__ __launch_bounds__(256) void InvertedBottleneck_conv_Q_13709535609694_kernel(
    const unsigned char* __restrict__ h2p, const float* __restrict__ W3f,
    const float* __restrict__ B3f, const float* __restrict__ x,
    float* __restrict__ out) {
  __shared__ float sW[16 * 384];
  __shared__ float sB[16];
  int tid = threadIdx.x;
  int o0 = blockIdx.y * 16;
  const float4* src4 = (const float4*)(W3f + o0 * 384);
  float4* dst4 = (float4*)sW;
  for (int i = tid; i < 1536; i += 256) dst4[i] = src4[i];
  if (tid < 16) sB[tid] = B3f[o0 + tid];
  __syncthreads();

  int pairid = blockIdx.x * 256 + tid;
  int n = pairid / PPI;
  int pp = pairid - n * PPI;
  const unsigned char* hb = h2p + (size_t)n * HID * PPI + pp;

  float acc0[16], acc1[16];
  #pragma unroll
  for (int o = 0; o < 16; o++) { acc0[o] = sB[o]; acc1[o] = sB[o]; }

  for (int ct = 0; ct < 24; ct++) {
    float v0[16], v1[16];
    #pragma unroll
    for (int c = 0; c < 16; c++) {
      unsigned int b = hb[(size_t)(ct * 16 + c) * PPI];
      v0[c] = (float)(b & 15u) * INV15;
      v1[c] = (float)(b >> 4) * INV15;
    }
    #pragma unroll
    for (int o = 0; o < 16; o++) {
      const float* wr = &sW[o * 384 + ct * 16];
      #pragma unroll
      for (int c = 0; c < 16; c++) { float w = wr[c]; acc0[o] += w * v0[c]; acc1[o] += w * v1[c]; }
    }
  }
  const float2* xs = (const float2*)(x + (size_t)n * CIN * HW + 2 * pp);
  float2* od = (float2*)(out + (size_t)n * CIN * HW + 2 * pp);
  #pragma unroll
  for (int o = 0; o < 16; o++) {
    float a0 = fminf(fmaxf(acc0[o], 0.f), 1.f);
    float a1 = fminf(fmaxf(acc1[o], 0.f), 1.f);
    float q0 = rintf(a0 * 15.f) * INV15;
    float q1 = rintf(a1 * 15.f) * INV15;
    float2 xv = xs[(size_t)(o0 + o) * (HW / 2)];
    float2 ov;
    ov.x = q0 + xv.x;
    ov.y = q1 + xv.y;
    od[(size_t)(o0 + o) * (HW / 2)] = ov;
  }
}

extern "C" void kernel_launch(void* const* d_in, const int* in_sizes, int n_in,
                              void* d_out, int out_size, void* d_ws, size_t ws_size,
                              hipStream_t stream) {
  const float* x  = (const float*)d_in[0];
  const float* w1 = (const float*)d_in[1];
  const float* w2 = (const float*)d_in[2];
  const float* w3 = (const float*)d_in[3];
  const float* g1 = (const float*)d_in[4];
  const float* b1 = (const float*)d_in[5];
  const float* m1 = (const float*)d_in[6];
  const float* v1 = (const float*)d_in[7];
  const float* g2 = (const float*)d_in[8];
  const float* b2 = (const float*)d_in[9];
  const float* m2 = (const float*)d_in[10];
  const float* v2 = (const float*)d_in[11];
  const float* g3 = (const float*)d_in[12];
  const float* b3 = (const float*)d_in[13];
  const float* m3 = (const float*)d_in[14];
  const float* v3 = (const float*)d_in[15];

  char* ws = (char*)d_ws;
  float* W1f = (float*)(ws + OFF_W1F);
  float* B1f = (float*)(ws + OFF_B1F);
  float* W2f = (float*)(ws + OFF_W2F);
  float* B2f = (float*)(ws + OFF_B2F);
  float* W3f = (float*)(ws + OFF_W3F);
  float* B3f = (float*)(ws + OFF_B3F);
  float* maxv = (float*)(ws + OFF_MAX);
  unsigned char* h1p = (unsigned char*)(ws + OFF_H1P);
  unsigned char* h2p = (unsigned char*)(ws + OFF_H2P);
  float* outp = (float*)d_out;

  prep_max<<<dim3(3), dim3(256), 0, stream>>>(w1, w2, w3, maxv);
  prep_quant<<<dim3(209), dim3(256), 0, stream>>>(
      w1, w2, w3, g1, b1, m1, v1, g2, b2, m2, v2, g3, b3, m3, v3,
      maxv, W1f, B1f, W2f, B2f, W3f, B3f);
  k1<<<dim3(196, 12), dim3(256), 0, stream>>>(x, W1f, B1f, h1p);
  k2<<<dim3(75264), dim3(256), 0, stream>>>(h1p, W2f, B2f, h2p);
  InvertedBottleneck_conv_Q_13709535609694_kernel<<<dim3(196, 4), dim3(256), 0, stream>>>(
      h2p, W3f, B3f, x, outp);
}

// Round 4
// 289.550 us; speedup vs baseline: 1.4689x; 1.4689x over previous
//
#include <hip/hip_runtime.h>
#include <hip/hip_bf16.h>

#define EPS 1e-5f
#define INV15 (1.0f/15.0f)

#define NB 32
#define CIN 64
#define HID 384
#define HH 56
#define HW 3136        // 56*56
#define PPI 1568       // pixel pairs per image
#define NPIX 100352    // NB*HW
#define BLKPB 1605632  // NPIX*16 bytes per 32-channel block (packed nibbles)
#define NPIXU4 401408  // NPIX*4 uints per 32-channel block

// ws layout (bytes)
#define OFF_W1F 0            // 24576 f
#define OFF_B1F 98304        // 384 f
#define OFF_W2T 99840        // 3456 f  (tap-major, even/odd-permuted, pre-folded *INV15)
#define OFF_B2F 113664       // 384 f   (even/odd-permuted)
#define OFF_BLOB 115200      // 25088 B: w3 i8 frags [12][4][64][8] + scale3[64] + bias3[64]
#define OFF_MAX 140288       // 3 f
#define OFF_H1 1048576       // 12 blocks * BLKPB = 19267584
#define OFF_H2 20316160      // 12 blocks * BLKPB

typedef int v4i __attribute__((ext_vector_type(4)));

__global__ __launch_bounds__(256) void prep_max(
    const float* __restrict__ w1, const float* __restrict__ w2,
    const float* __restrict__ w3, float* __restrict__ maxout) {
  __shared__ float red[256];
  int t = threadIdx.x;
  int b = blockIdx.x;
  const float* src = (b == 0) ? w1 : (b == 1) ? w2 : w3;
  int n = (b == 1) ? HID * 9 : HID * CIN;
  float m = 0.f;
  for (int i = t; i < n; i += 256)
    m = fmaxf(m, fabsf(tanhf(src[i])));
  red[t] = m; __syncthreads();
  for (int s = 128; s > 0; s >>= 1) {
    if (t < s) red[t] = fmaxf(red[t], red[t + s]);
    __syncthreads();
  }
  if (t == 0) maxout[b] = red[0];
}

// ranges: [0,24576) W1f | [24576,28032) W2t | [28032,28416) B1f |
// [28416,28800) B2f | [28800,53376) w3 i8 frag | [53376,53440) scale3 | [53440,53504) bias3
__global__ __launch_bounds__(256) void prep_quant(
    const float* __restrict__ w1, const float* __restrict__ w2,
    const float* __restrict__ w3,
    const float* __restrict__ g1, const float* __restrict__ b1,
    const float* __restrict__ m1, const float* __restrict__ v1,
    const float* __restrict__ g2, const float* __restrict__ b2,
    const float* __restrict__ m2, const float* __restrict__ v2,
    const float* __restrict__ g3, const float* __restrict__ b3,
    const float* __restrict__ m3, const float* __restrict__ v3,
    const float* __restrict__ maxv,
    float* __restrict__ W1f, float* __restrict__ B1f,
    float* __restrict__ W2t, float* __restrict__ B2f,
    char* __restrict__ blob) {
  int idx = blockIdx.x * 256 + threadIdx.x;
  if (idx < 24576) {                      // W1f: [384][64] folded fp32
    int o = idx >> 6;
    float s = g1[o] / sqrtf(v1[o] + EPS);
    float t = tanhf(w1[idx]);
    float q = 2.f * (rintf((t / (2.f * maxv[0]) + 0.5f) * 15.f) * INV15) - 1.f;
    W1f[idx] = q * s;
  } else if (idx < 28032) {               // W2t[tap][384] even/odd-permuted, *INV15
    int jj = idx - 24576;
    int tap = jj / 384; int cl = jj - tap * 384;
    int g = cl >> 3; int r = cl & 7;
    int c = g * 8 + ((r < 4) ? (r + r) : (((r - 4) << 1) + 1));
    float s = g2[c] / sqrtf(v2[c] + EPS);
    float t = tanhf(w2[c * 9 + tap]);
    float q = 2.f * (rintf((t / (2.f * maxv[1]) + 0.5f) * 15.f) * INV15) - 1.f;
    W2t[jj] = q * s * INV15;
  } else if (idx < 28416) {               // B1f
    int o = idx - 28032;
    float s = g1[o] / sqrtf(v1[o] + EPS);
    B1f[o] = b1[o] - m1[o] * s;
  } else if (idx < 28800) {               // B2f permuted
    int cl = idx - 28416;
    int g = cl >> 3; int r = cl & 7;
    int c = g * 8 + ((r < 4) ? (r + r) : (((r - 4) << 1) + 1));
    float s = g2[c] / sqrtf(v2[c] + EPS);
    B2f[cl] = b2[c] - m2[c] * s;
  } else if (idx < 53376) {               // w3 i8 frag image [ks][nt][lane][8]
    int jj = idx - 28800;
    int lane_j = jj & 7;
    int lane = (jj >> 3) & 63;
    int nt = (jj >> 9) & 3;
    int ks = jj >> 11;                    // 0..11
    int n = nt * 16 + (lane & 15);
    int k = ks * 32 + (lane >> 4) * 8 + lane_j;
    float t = tanhf(w3[n * 384 + k]);
    int w_int = 2 * (int)rintf((t / (2.f * maxv[2]) + 0.5f) * 15.f) - 15;
    blob[jj] = (char)w_int;
  } else if (idx < 53440) {               // scale3 = s3/225
    int n = idx - 53376;
    float s = g3[n] / sqrtf(v3[n] + EPS);
    *(float*)(blob + 24576 + n * 4) = s * (1.f / 225.f);
  } else if (idx < 53504) {               // bias3
    int n = idx - 53440;
    float s = g3[n] / sqrtf(v3[n] + EPS);
    *(float*)(blob + 24832 + n * 4) = b3[n] - m3[n] * s;
  }
}

// conv1 1x1 (64->384) + bn + relu + act_quant -> packed nibbles, 32ch-blocked NHWC
__global__ __launch_bounds__(256) void k1(
    const float* __restrict__ x, const float* __restrict__ W1f,
    const float* __restrict__ B1f, char* __restrict__ h1b) {
  __shared__ float sW[32 * 64];
  __shared__ float sB[32];
  int tid = threadIdx.x;
  int o0 = blockIdx.y * 32;
  const float4* src4 = (const float4*)(W1f + o0 * 64);
  float4* dst4 = (float4*)sW;
  for (int i = tid; i < 512; i += 256) dst4[i] = src4[i];
  if (tid < 32) sB[tid] = B1f[o0 + tid];
  __syncthreads();

  int pairid = blockIdx.x * 256 + tid;
  int n = pairid / PPI;
  int pp = pairid - n * PPI;
  const float* xb = x + (size_t)n * CIN * HW + 2 * pp;

  float acc0[32], acc1[32];
  #pragma unroll
  for (int o = 0; o < 32; o++) { acc0[o] = sB[o]; acc1[o] = sB[o]; }

  for (int ct = 0; ct < 4; ct++) {
    float x0[16], x1[16];
    #pragma unroll
    for (int c = 0; c < 16; c++) {
      float2 xv = *(const float2*)(xb + (size_t)(ct * 16 + c) * HW);
      x0[c] = xv.x; x1[c] = xv.y;
    }
    #pragma unroll
    for (int o = 0; o < 32; o++) {
      const float* wr = &sW[o * 64 + ct * 16];
      #pragma unroll
      for (int c = 0; c < 16; c++) { float w = wr[c]; acc0[o] += w * x0[c]; acc1[o] += w * x1[c]; }
    }
  }
  unsigned int d0[4] = {0,0,0,0}, d1[4] = {0,0,0,0};
  #pragma unroll
  for (int o = 0; o < 32; o++) {
    float a0 = fminf(fmaxf(acc0[o], 0.f), 1.f);
    float a1 = fminf(fmaxf(acc1[o], 0.f), 1.f);
    unsigned int q0 = (unsigned int)(int)rintf(a0 * 15.f);
    unsigned int q1 = (unsigned int)(int)rintf(a1 * 15.f);
    d0[o >> 3] |= q0 << ((o & 7) * 4);
    d1[o >> 3] |= q1 << ((o & 7) * 4);
  }
  size_t pixabs = (size_t)n * HW + 2 * pp;
  uint4* dst = (uint4*)(h1b + (size_t)blockIdx.y * BLKPB + pixabs * 16);
  uint4 s0; s0.x = d0[0]; s0.y = d0[1]; s0.z = d0[2]; s0.w = d0[3];
  uint4 s1; s1.x = d1[0]; s1.y = d1[1]; s1.z = d1[2]; s1.w = d1[3];
  dst[0] = s0;
  dst[1] = s1;
}

// depthwise 3x3 + bn + relu + act_quant, nibble-packed blocked layout in/out
// grid (6272, 3): block = 16 px x 16 channel-groups(8ch)
__global__ __launch_bounds__(256) void k2(
    const unsigned int* __restrict__ h1q, const float* __restrict__ W2t,
    const float* __restrict__ B2f, unsigned int* __restrict__ h2q) {
  int tid = threadIdx.x;
  int g = blockIdx.y * 16 + (tid & 15);       // 0..47
  int img = blockIdx.x / 196;
  int trem = blockIdx.x - img * 196;
  int pixrem = trem * 16 + (tid >> 4);        // 0..3135
  int h = pixrem / 56;
  int w = pixrem - h * 56;
  size_t base_u = (size_t)(g >> 2) * NPIXU4 + (g & 3);
  size_t pixabs = (size_t)img * HW + pixrem;

  float4 be = *(const float4*)(B2f + g * 8);
  float4 bo = *(const float4*)(B2f + g * 8 + 4);
  float aE0 = be.x, aE1 = be.y, aE2 = be.z, aE3 = be.w;
  float aO0 = bo.x, aO1 = bo.y, aO2 = bo.z, aO3 = bo.w;

  #pragma unroll
  for (int tap = 0; tap < 9; tap++) {
    const int dh = tap / 3 - 1;
    const int dw = tap % 3 - 1;
    bool valid = ((unsigned)(h + dh) < 56u) && ((unsigned)(w + dw) < 56u);
    unsigned int u = 0u;
    if (valid) u = h1q[base_u + (pixabs + dh * 56 + dw) * 4];
    unsigned int te = u & 0x0F0F0F0Fu;
    unsigned int to = (u >> 4) & 0x0F0F0F0Fu;
    float4 wE = *(const float4*)(W2t + tap * 384 + g * 8);
    float4 wO = *(const float4*)(W2t + tap * 384 + g * 8 + 4);
    aE0 += wE.x * (float)(unsigned char)(te);
    aE1 += wE.y * (float)(unsigned char)(te >> 8);
    aE2 += wE.z * (float)(unsigned char)(te >> 16);
    aE3 += wE.w * (float)(unsigned char)(te >> 24);
    aO0 += wO.x * (float)(unsigned char)(to);
    aO1 += wO.y * (float)(unsigned char)(to >> 8);
    aO2 += wO.z * (float)(unsigned char)(to >> 16);
    aO3 += wO.w * (float)(unsigned char)(to >> 24);
  }
  unsigned int pk = 0;
  {
    unsigned int q;
    q = (unsigned int)(int)rintf(fminf(fmaxf(aE0, 0.f), 1.f) * 15.f); pk |= q;
    q = (unsigned int)(int)rintf(fminf(fmaxf(aO0, 0.f), 1.f) * 15.f); pk |= q << 4;
    q = (unsigned int)(int)rintf(fminf(fmaxf(aE1, 0.f), 1.f) * 15.f); pk |= q << 8;
    q = (unsigned int)(int)rintf(fminf(fmaxf(aO1, 0.f), 1.f) * 15.f); pk |= q << 12;
    q = (unsigned int)(int)rintf(fminf(fmaxf(aE2, 0.f), 1.f) * 15.f); pk |= q << 16;
    q = (unsigned int)(int)rintf(fminf(fmaxf(aO2, 0.f), 1.f) * 15.f); pk |= q << 20;
    q = (unsigned int)(int)rintf(fminf(fmaxf(aE3, 0.f), 1.f) * 15.f); pk |= q << 24;
    q = (unsigned int)(int)rintf(fminf(fmaxf(aO3, 0.f), 1.f) * 15.f); pk |= q << 28;
  }
  h2q[base_u + pixabs * 4] = pk;
}

// conv3 1x1 (384->64) via i8 MFMA (exact) + bn + act_quant + residual -> fp32 out
// grid (1568): block = 4 waves x 16 px = 64 px
__global__ __launch_bounds__(256) void InvertedBottleneck_conv_Q_13709535609694_kernel(
    const unsigned int* __restrict__ h2q, const char* __restrict__ blob,
    const float* __restrict__ x, float* __restrict__ out) {
  __shared__ long lds8[3136];   // 24576 B frags + 256 B scale3 + 256 B bias3
  int tid = threadIdx.x;
  {
    const long* src = (const long*)blob;
    #pragma unroll
    for (int i = 0; i < 13; i++) {
      int j = tid + i * 256;
      if (j < 3136) lds8[j] = src[j];
    }
  }
  __syncthreads();

  int wv = tid >> 6;
  int lane = tid & 63;
  int m = lane & 15;
  int quad = lane >> 4;
  int pixW = blockIdx.x * 64 + wv * 16;

  const unsigned int* aptr = h2q + (size_t)(pixW + m) * 4 + quad;
  unsigned int ua[12];
  #pragma unroll
  for (int ks = 0; ks < 12; ks++) ua[ks] = aptr[(size_t)ks * NPIXU4];

  v4i acc[4];
  #pragma unroll
  for (int nt = 0; nt < 4; nt++) { v4i z = {0,0,0,0}; acc[nt] = z; }

  #pragma unroll
  for (int ks = 0; ks < 12; ks++) {
    unsigned int u = ua[ks];
    unsigned int t = u & 0x0F0F0F0Fu;
    unsigned int s = (u >> 4) & 0x0F0F0F0Fu;
    unsigned int d0 = (t & 0xFFu) | ((s & 0xFFu) << 8) | ((t & 0xFF00u) << 8) | ((s & 0xFF00u) << 16);
    unsigned int d1 = ((t >> 16) & 0xFFu) | (((s >> 16) & 0xFFu) << 8) | ((t >> 24) << 16) | ((s >> 24) << 24);
    long aF = (long)(((unsigned long)d1 << 32) | (unsigned long)d0);
    #pragma unroll
    for (int nt = 0; nt < 4; nt++) {
      long bF = lds8[(ks * 4 + nt) * 64 + lane];
      acc[nt] = __builtin_amdgcn_mfma_i32_16x16x32_i8(aF, bF, acc[nt], 0, 0, 0);
    }
  }

  const float* scl = (const float*)(lds8 + 3072);   // scale3[64] then bias3[64]
  int img = blockIdx.x / 49;
  int prem = (blockIdx.x - img * 49) * 64 + wv * 16 + quad * 4;

  #pragma unroll
  for (int nt = 0; nt < 4; nt++) {
    int n = nt * 16 + m;
    float sc = scl[n];
    float bi = scl[64 + n];
    size_t off = ((size_t)img * CIN + n) * HW + prem;
    const float4 xv = *(const float4*)(x + off);
    float4 ov;
    float v, a;
    v = (float)acc[nt][0] * sc + bi; a = fminf(fmaxf(v, 0.f), 1.f); ov.x = rintf(a * 15.f) * INV15 + xv.x;
    v = (float)acc[nt][1] * sc + bi; a = fminf(fmaxf(v, 0.f), 1.f); ov.y = rintf(a * 15.f) * INV15 + xv.y;
    v = (float)acc[nt][2] * sc + bi; a = fminf(fmaxf(v, 0.f), 1.f); ov.z = rintf(a * 15.f) * INV15 + xv.z;
    v = (float)acc[nt][3] * sc + bi; a = fminf(fmaxf(v, 0.f), 1.f); ov.w = rintf(a * 15.f) * INV15 + xv.w;
    *(float4*)(out + off) = ov;
  }
}

extern "C" void kernel_launch(void* const* d_in, const int* in_sizes, int n_in,
                              void* d_out, int out_size, void* d_ws, size_t ws_size,
                              hipStream_t stream) {
  const float* x  = (const float*)d_in[0];
  const float* w1 = (const float*)d_in[1];
  const float* w2 = (const float*)d_in[2];
  const float* w3 = (const float*)d_in[3];
  const float* g1 = (const float*)d_in[4];
  const float* b1 = (const float*)d_in[5];
  const float* m1 = (const float*)d_in[6];
  const float* v1 = (const float*)d_in[7];
  const float* g2 = (const float*)d_in[8];
  const float* b2 = (const float*)d_in[9];
  const float* m2 = (const float*)d_in[10];
  const float* v2 = (const float*)d_in[11];
  const float* g3 = (const float*)d_in[12];
  const float* b3 = (const float*)d_in[13];
  const float* m3 = (const float*)d_in[14];
  const float* v3 = (const float*)d_in[15];

  char* ws = (char*)d_ws;
  float* W1f = (float*)(ws + OFF_W1F);
  float* B1f = (float*)(ws + OFF_B1F);
  float* W2t = (float*)(ws + OFF_W2T);
  float* B2f = (float*)(ws + OFF_B2F);
  char*  blob = ws + OFF_BLOB;
  float* maxv = (float*)(ws + OFF_MAX);
  char*  h1b = ws + OFF_H1;
  char*  h2b = ws + OFF_H2;
  float* outp = (float*)d_out;

  prep_max<<<dim3(3), dim3(256), 0, stream>>>(w1, w2, w3, maxv);
  prep_quant<<<dim3(209), dim3(256), 0, stream>>>(
      w1, w2, w3, g1, b1, m1, v1, g2, b2, m2, v2, g3, b3, m3, v3,
      maxv, W1f, B1f, W2t, B2f, blob);
  k1<<<dim3(196, 12), dim3(256), 0, stream>>>(x, W1f, B1f, h1b);
  k2<<<dim3(6272, 3), dim3(256), 0, stream>>>(
      (const unsigned int*)h1b, W2t, B2f, (unsigned int*)h2b);
  InvertedBottleneck_conv_Q_13709535609694_kernel<<<dim3(1568), dim3(256), 0, stream>>>(
      (const unsigned int*)h2b, blob, x, outp);
}

// Round 5
// 205.959 us; speedup vs baseline: 2.0651x; 1.4059x over previous
//
#include <hip/hip_runtime.h>
#include <hip/hip_bf16.h>

#define EPS 1e-5f
#define INV15 (1.0f/15.0f)

#define NB 32
#define CIN 64
#define HID 384
#define HH 56
#define HW 3136        // 56*56
#define NPIX 100352    // NB*HW
#define BLKPB 1605632  // NPIX*16 bytes per 32-channel block (packed nibbles)
#define NPIXU4 401408  // NPIX*4 uints per 32-channel block

// ws layout (bytes), all 16B-aligned
#define OFF_BLOB1 0          // 52224: W1frag bf16 [24mt][2ks][64lane][8e] (49152) + sc15[384]f + bi15[384]f
#define OFF_W2T  52224       // 13824: W2t[9tap][48g][8] floats, nibble-permuted, prefolded *INV15
#define OFF_B2F  66048       // 1536:  B2f[48g][8] floats, same permutation
#define OFF_BLOB3 67584      // 25088: w3 i8 frags [12ks][4nt][64lane][8j] + scale3[64] + bias3[64]
#define OFF_MAX  92672       // 12: uint-as-float maxes
#define OFF_H1 1048576       // 12 blocks * BLKPB
#define OFF_H2 20316160      // 12 blocks * BLKPB

typedef int v4i __attribute__((ext_vector_type(4)));
typedef float f32x4 __attribute__((ext_vector_type(4)));
typedef short bf16x8 __attribute__((ext_vector_type(8)));

__device__ __forceinline__ short splitbf(float f, float& rem) {
  __hip_bfloat16 h = __float2bfloat16(f);
  rem = f - __bfloat162float(h);
  return __builtin_bit_cast(short, h);
}

// 48 blocks: 16 per tensor, atomicMax(uint) of |tanh(w)| (non-negative -> bit-monotone)
__global__ __launch_bounds__(256) void prep_max(
    const float* __restrict__ w1, const float* __restrict__ w2,
    const float* __restrict__ w3, unsigned int* __restrict__ maxout) {
  int b = blockIdx.x >> 4;
  int sub = blockIdx.x & 15;
  const float* src = (b == 0) ? w1 : (b == 1) ? w2 : w3;
  int n = (b == 1) ? HID * 9 : HID * CIN;
  float m = 0.f;
  for (int i = sub * 256 + threadIdx.x; i < n; i += 4096)
    m = fmaxf(m, fabsf(tanhf(src[i])));
  #pragma unroll
  for (int off = 32; off > 0; off >>= 1)
    m = fmaxf(m, __shfl_down(m, off, 64));
  __shared__ float red[4];
  if ((threadIdx.x & 63) == 0) red[threadIdx.x >> 6] = m;
  __syncthreads();
  if (threadIdx.x == 0) {
    m = fmaxf(fmaxf(red[0], red[1]), fmaxf(red[2], red[3]));
    atomicMax(maxout + b, __float_as_uint(m));
  }
}

// builds all folded/permuted weight blobs. 53888 elements -> 211 blocks.
__global__ __launch_bounds__(256) void prep_quant(
    const float* __restrict__ w1, const float* __restrict__ w2,
    const float* __restrict__ w3,
    const float* __restrict__ g1, const float* __restrict__ b1,
    const float* __restrict__ m1, const float* __restrict__ v1,
    const float* __restrict__ g2, const float* __restrict__ b2,
    const float* __restrict__ m2, const float* __restrict__ v2,
    const float* __restrict__ g3, const float* __restrict__ b3,
    const float* __restrict__ m3, const float* __restrict__ v3,
    char* __restrict__ ws) {
  const float* maxv = (const float*)(ws + OFF_MAX);
  int idx = blockIdx.x * 256 + threadIdx.x;
  if (idx < 24576) {                      // W1frag bf16 (exact odd ints -15..15)
    int e = idx & 7, lane = (idx >> 3) & 63, ks = (idx >> 9) & 1, mt = idx >> 10;
    int o = mt * 16 + (lane & 15);
    int k = ks * 32 + (lane >> 4) * 8 + e;
    float t = tanhf(w1[o * 64 + k]);
    int wi = 2 * (int)rintf((t / (2.f * maxv[0]) + 0.5f) * 15.f) - 15;
    float rr;
    ((short*)(ws + OFF_BLOB1))[idx] = splitbf((float)wi, rr);
  } else if (idx < 28032) {               // W2t[tap][g][8]: [E0..E3,O0..O3]
    int jj = idx - 24576;
    int tap = jj / 384, cl = jj - tap * 384;
    int g = cl >> 3, r = cl & 7;
    int c = 32 * (g >> 2) + ((r < 4) ? ((g & 3) * 4 + r) : (16 + (g & 3) * 4 + (r - 4)));
    float s = g2[c] / sqrtf(v2[c] + EPS);
    float t = tanhf(w2[c * 9 + tap]);
    float q = 2.f * (rintf((t / (2.f * maxv[1]) + 0.5f) * 15.f) * INV15) - 1.f;
    ((float*)(ws + OFF_W2T))[jj] = q * s * INV15;
  } else if (idx < 28416) {               // B2f same permutation
    int cl = idx - 28032;
    int g = cl >> 3, r = cl & 7;
    int c = 32 * (g >> 2) + ((r < 4) ? ((g & 3) * 4 + r) : (16 + (g & 3) * 4 + (r - 4)));
    float s = g2[c] / sqrtf(v2[c] + EPS);
    ((float*)(ws + OFF_B2F))[cl] = b2[c] - m2[c] * s;
  } else if (idx < 28800) {               // sc15 = s1
    int o = idx - 28416;
    ((float*)(ws + OFF_BLOB1 + 49152))[o] = g1[o] / sqrtf(v1[o] + EPS);
  } else if (idx < 29184) {               // bi15 = 15*(b1 - m1*s1)
    int o = idx - 28800;
    float s = g1[o] / sqrtf(v1[o] + EPS);
    ((float*)(ws + OFF_BLOB1 + 50688))[o] = 15.f * (b1[o] - m1[o] * s);
  } else if (idx < 53760) {               // w3 i8 frags, nibble-permuted k
    int jj = idx - 29184;
    int j = jj & 7, lane = (jj >> 3) & 63, nt = (jj >> 9) & 3, ks = jj >> 11;
    int n = nt * 16 + (lane & 15);
    int quad = lane >> 4;
    int k = ks * 32 + ((j & 1) ? (16 + quad * 4 + (j >> 1)) : (quad * 4 + (j >> 1)));
    float t = tanhf(w3[n * 384 + k]);
    int wi = 2 * (int)rintf((t / (2.f * maxv[2]) + 0.5f) * 15.f) - 15;
    (ws + OFF_BLOB3)[jj] = (char)wi;
  } else if (idx < 53824) {               // scale3 = s3/225
    int n = idx - 53760;
    float s = g3[n] / sqrtf(v3[n] + EPS);
    *(float*)(ws + OFF_BLOB3 + 24576 + n * 4) = s * (1.f / 225.f);
  } else if (idx < 53888) {               // bias3
    int n = idx - 53824;
    float s = g3[n] / sqrtf(v3[n] + EPS);
    *(float*)(ws + OFF_BLOB3 + 24832 + n * 4) = b3[n] - m3[n] * s;
  }
}

// conv1 1x1 (64->384) via bf16 MFMA (x = hi+lo+lo2, exact int weights) + bn + relu
// + act_quant -> packed nibbles. grid 1568 blocks x 64 px; wave = 16 px.
__global__ __launch_bounds__(256) void k1(
    const float* __restrict__ x, const char* __restrict__ blob1,
    char* __restrict__ h1b) {
  __shared__ uint4 sBuf[3264];    // 49152B wfrags + 1536B sc15 + 1536B bi15
  int tid = threadIdx.x;
  {
    const uint4* src = (const uint4*)blob1;
    for (int i = tid; i < 3264; i += 256) sBuf[i] = src[i];
  }
  __syncthreads();
  const bf16x8* wf = (const bf16x8*)sBuf;
  const float* sSB = (const float*)(sBuf + 3072);   // [0..383]=sc15, [384..767]=bi15

  int wv = tid >> 6, lane = tid & 63;
  int quad = lane >> 4, m = lane & 15;
  size_t pixabs = (size_t)blockIdx.x * 64 + wv * 16 + m;
  int img = blockIdx.x / 49;
  int prem = (blockIdx.x - img * 49) * 64 + wv * 16 + m;
  const float* xb = x + (size_t)img * (CIN * HW) + prem;

  // x fragments: 3-way bf16 split, K=64 (2 ks-steps)
  bf16x8 xh[2], xl[2], xq[2];
  #pragma unroll
  for (int ks = 0; ks < 2; ks++) {
    #pragma unroll
    for (int e = 0; e < 8; e++) {
      float f = xb[(size_t)(ks * 32 + quad * 8 + e) * HW];
      float r1, r2, r3;
      xh[ks][e] = splitbf(f, r1);
      xl[ks][e] = splitbf(r1, r2);
      xq[ks][e] = splitbf(r2, r3);
    }
  }

  #pragma unroll
  for (int half = 0; half < 2; half++) {
    f32x4 acc[12];
    #pragma unroll
    for (int i = 0; i < 12; i++) { f32x4 z = {0.f, 0.f, 0.f, 0.f}; acc[i] = z; }
    #pragma unroll
    for (int i = 0; i < 12; i++) {
      int mt = half * 12 + i;
      bf16x8 w0 = wf[(mt * 2 + 0) * 64 + lane];
      bf16x8 w1 = wf[(mt * 2 + 1) * 64 + lane];
      acc[i] = __builtin_amdgcn_mfma_f32_16x16x32_bf16(w0, xh[0], acc[i], 0, 0, 0);
      acc[i] = __builtin_amdgcn_mfma_f32_16x16x32_bf16(w1, xh[1], acc[i], 0, 0, 0);
      acc[i] = __builtin_amdgcn_mfma_f32_16x16x32_bf16(w0, xl[0], acc[i], 0, 0, 0);
      acc[i] = __builtin_amdgcn_mfma_f32_16x16x32_bf16(w1, xl[1], acc[i], 0, 0, 0);
      acc[i] = __builtin_amdgcn_mfma_f32_16x16x32_bf16(w0, xq[0], acc[i], 0, 0, 0);
      acc[i] = __builtin_amdgcn_mfma_f32_16x16x32_bf16(w1, xq[1], acc[i], 0, 0, 0);
    }
    // epilogue: 6 channel-blocks per half; lane packs 8 nibbles -> 1 uint
    #pragma unroll
    for (int l = 0; l < 6; l++) {
      int b = half * 6 + l;
      f32x4 ae = acc[2 * l], ao = acc[2 * l + 1];
      unsigned int pk = 0;
      #pragma unroll
      for (int r = 0; r < 4; r++) {
        int oe = 32 * b + quad * 4 + r;
        int oo = oe + 16;
        float fe = fminf(fmaxf(ae[r] * sSB[oe] + sSB[384 + oe], 0.f), 15.f);
        float fo = fminf(fmaxf(ao[r] * sSB[oo] + sSB[384 + oo], 0.f), 15.f);
        pk |= ((unsigned int)(int)rintf(fe)) << (8 * r);
        pk |= ((unsigned int)(int)rintf(fo)) << (8 * r + 4);
      }
      *(unsigned int*)(h1b + (size_t)b * BLKPB + pixabs * 16 + quad * 4) = pk;
    }
  }
}

// depthwise 3x3 + bn + relu + act_quant, nibble-packed blocked layout in/out
// grid (6272, 3): block = 16 px x 16 channel-groups(8ch)
__global__ __launch_bounds__(256) void k2(
    const unsigned int* __restrict__ h1q, const float* __restrict__ W2t,
    const float* __restrict__ B2f, unsigned int* __restrict__ h2q) {
  int tid = threadIdx.x;
  int g = blockIdx.y * 16 + (tid & 15);       // 0..47
  int img = blockIdx.x / 196;
  int trem = blockIdx.x - img * 196;
  int pixrem = trem * 16 + (tid >> 4);        // 0..3135
  int h = pixrem / 56;
  int w = pixrem - h * 56;
  size_t base_u = (size_t)(g >> 2) * NPIXU4 + (g & 3);
  size_t pixabs = (size_t)img * HW + pixrem;

  float4 be = *(const float4*)(B2f + g * 8);
  float4 bo = *(const float4*)(B2f + g * 8 + 4);
  float aE0 = be.x, aE1 = be.y, aE2 = be.z, aE3 = be.w;
  float aO0 = bo.x, aO1 = bo.y, aO2 = bo.z, aO3 = bo.w;

  #pragma unroll
  for (int tap = 0; tap < 9; tap++) {
    const int dh = tap / 3 - 1;
    const int dw = tap % 3 - 1;
    bool valid = ((unsigned)(h + dh) < 56u) && ((unsigned)(w + dw) < 56u);
    unsigned int u = 0u;
    if (valid) u = h1q[base_u + (pixabs + dh * 56 + dw) * 4];
    unsigned int te = u & 0x0F0F0F0Fu;
    unsigned int to = (u >> 4) & 0x0F0F0F0Fu;
    float4 wE = *(const float4*)(W2t + tap * 384 + g * 8);
    float4 wO = *(const float4*)(W2t + tap * 384 + g * 8 + 4);
    aE0 += wE.x * (float)(unsigned char)(te);
    aE1 += wE.y * (float)(unsigned char)(te >> 8);
    aE2 += wE.z * (float)(unsigned char)(te >> 16);
    aE3 += wE.w * (float)(unsigned char)(te >> 24);
    aO0 += wO.x * (float)(unsigned char)(to);
    aO1 += wO.y * (float)(unsigned char)(to >> 8);
    aO2 += wO.z * (float)(unsigned char)(to >> 16);
    aO3 += wO.w * (float)(unsigned char)(to >> 24);
  }
  unsigned int pk = 0;
  {
    unsigned int q;
    q = (unsigned int)(int)rintf(fminf(fmaxf(aE0, 0.f), 1.f) * 15.f); pk |= q;
    q = (unsigned int)(int)rintf(fminf(fmaxf(aO0, 0.f), 1.f) * 15.f); pk |= q << 4;
    q = (unsigned int)(int)rintf(fminf(fmaxf(aE1, 0.f), 1.f) * 15.f); pk |= q << 8;
    q = (unsigned int)(int)rintf(fminf(fmaxf(aO1, 0.f), 1.f) * 15.f); pk |= q << 12;
    q = (unsigned int)(int)rintf(fminf(fmaxf(aE2, 0.f), 1.f) * 15.f); pk |= q << 16;
    q = (unsigned int)(int)rintf(fminf(fmaxf(aO2, 0.f), 1.f) * 15.f); pk |= q << 20;
    q = (unsigned int)(int)rintf(fminf(fmaxf(aE3, 0.f), 1.f) * 15.f); pk |= q << 24;
    q = (unsigned int)(int)rintf(fminf(fmaxf(aO3, 0.f), 1.f) * 15.f); pk |= q << 28;
  }
  h2q[base_u + pixabs * 4] = pk;
}

// conv3 1x1 (384->64) via i8 MFMA (exact) + bn + act_quant + residual -> fp32 out
__global__ __launch_bounds__(256) void InvertedBottleneck_conv_Q_13709535609694_kernel(
    const unsigned int* __restrict__ h2q, const char* __restrict__ blob,
    const float* __restrict__ x, float* __restrict__ out) {
  __shared__ long lds8[3136];   // 24576 B frags + 256 B scale3 + 256 B bias3
  int tid = threadIdx.x;
  {
    const long* src = (const long*)blob;
    #pragma unroll
    for (int i = 0; i < 13; i++) {
      int j = tid + i * 256;
      if (j < 3136) lds8[j] = src[j];
    }
  }
  __syncthreads();

  int wv = tid >> 6;
  int lane = tid & 63;
  int m = lane & 15;
  int quad = lane >> 4;
  int pixW = blockIdx.x * 64 + wv * 16;

  const unsigned int* aptr = h2q + (size_t)(pixW + m) * 4 + quad;
  unsigned int ua[12];
  #pragma unroll
  for (int ks = 0; ks < 12; ks++) ua[ks] = aptr[(size_t)ks * NPIXU4];

  v4i acc[4];
  #pragma unroll
  for (int nt = 0; nt < 4; nt++) { v4i z = {0,0,0,0}; acc[nt] = z; }

  #pragma unroll
  for (int ks = 0; ks < 12; ks++) {
    unsigned int u = ua[ks];
    unsigned int t = u & 0x0F0F0F0Fu;
    unsigned int s = (u >> 4) & 0x0F0F0F0Fu;
    unsigned int d0 = (t & 0xFFu) | ((s & 0xFFu) << 8) | ((t & 0xFF00u) << 8) | ((s & 0xFF00u) << 16);
    unsigned int d1 = ((t >> 16) & 0xFFu) | (((s >> 16) & 0xFFu) << 8) | ((t >> 24) << 16) | ((s >> 24) << 24);
    long aF = (long)(((unsigned long)d1 << 32) | (unsigned long)d0);
    #pragma unroll
    for (int nt = 0; nt < 4; nt++) {
      long bF = lds8[(ks * 4 + nt) * 64 + lane];
      acc[nt] = __builtin_amdgcn_mfma_i32_16x16x32_i8(aF, bF, acc[nt], 0, 0, 0);
    }
  }

  const float* scl = (const float*)(lds8 + 3072);   // scale3[64] then bias3[64]
  int img = blockIdx.x / 49;
  int prem = (blockIdx.x - img * 49) * 64 + wv * 16 + quad * 4;

  #pragma unroll
  for (int nt = 0; nt < 4; nt++) {
    int n = nt * 16 + m;
    float sc = scl[n];
    float bi = scl[64 + n];
    size_t off = ((size_t)img * CIN + n) * HW + prem;
    const float4 xv = *(const float4*)(x + off);
    float4 ov;
    float v, a;
    v = (float)acc[nt][0] * sc + bi; a = fminf(fmaxf(v, 0.f), 1.f); ov.x = rintf(a * 15.f) * INV15 + xv.x;
    v = (float)acc[nt][1] * sc + bi; a = fminf(fmaxf(v, 0.f), 1.f); ov.y = rintf(a * 15.f) * INV15 + xv.y;
    v = (float)acc[nt][2] * sc + bi; a = fminf(fmaxf(v, 0.f), 1.f); ov.z = rintf(a * 15.f) * INV15 + xv.z;
    v = (float)acc[nt][3] * sc + bi; a = fminf(fmaxf(v, 0.f), 1.f); ov.w = rintf(a * 15.f) * INV15 + xv.w;
    *(float4*)(out + off) = ov;
  }
}

extern "C" void kernel_launch(void* const* d_in, const int* in_sizes, int n_in,
                              void* d_out, int out_size, void* d_ws, size_t ws_size,
                              hipStream_t stream) {
  const float* x  = (const float*)d_in[0];
  const float* w1 = (const float*)d_in[1];
  const float* w2 = (const float*)d_in[2];
  const float* w3 = (const float*)d_in[3];
  const float* g1 = (const float*)d_in[4];
  const float* b1 = (const float*)d_in[5];
  const float* m1 = (const float*)d_in[6];
  const float* v1 = (const float*)d_in[7];
  const float* g2 = (const float*)d_in[8];
  const float* b2 = (const float*)d_in[9];
  const float* m2 = (const float*)d_in[10];
  const float* v2 = (const float*)d_in[11];
  const float* g3 = (const float*)d_in[12];
  const float* b3 = (const float*)d_in[13];
  const float* m3 = (const float*)d_in[14];
  const float* v3 = (const float*)d_in[15];

  char* ws = (char*)d_ws;
  unsigned int* maxu = (unsigned int*)(ws + OFF_MAX);
  char* h1b = ws + OFF_H1;
  char* h2b = ws + OFF_H2;
  float* outp = (float*)d_out;

  hipMemsetAsync(maxu, 0, 12, stream);
  prep_max<<<dim3(48), dim3(256), 0, stream>>>(w1, w2, w3, maxu);
  prep_quant<<<dim3(211), dim3(256), 0, stream>>>(
      w1, w2, w3, g1, b1, m1, v1, g2, b2, m2, v2, g3, b3, m3, v3, ws);
  k1<<<dim3(1568), dim3(256), 0, stream>>>(x, ws + OFF_BLOB1, h1b);
  k2<<<dim3(6272, 3), dim3(256), 0, stream>>>(
      (const unsigned int*)h1b, (const float*)(ws + OFF_W2T),
      (const float*)(ws + OFF_B2F), (unsigned int*)h2b);
  InvertedBottleneck_conv_Q_13709535609694_kernel<<<dim3(1568), dim3(256), 0, stream>>>(
      (const unsigned int*)h2b, ws + OFF_BLOB3, x, outp);
}

// Round 6
// 170.214 us; speedup vs baseline: 2.4988x; 1.2100x over previous
//
#include <hip/hip_runtime.h>
#include <hip/hip_bf16.h>

#define EPS 1e-5f
#define INV15 (1.0f/15.0f)

#define NB 32
#define CIN 64
#define HID 384
#define HH 56
#define HW 3136        // 56*56
#define NPIX 100352    // NB*HW
#define BLKPB 1605632  // NPIX*16 bytes per 32-channel block (packed nibbles)
#define NPIXU4 401408  // NPIX*4 uints per 32-channel block

// ws layout (bytes), all 16B-aligned
#define OFF_BLOB1 0          // 52224: W1frag bf16 [24mt][2ks][64lane][8e] (49152) + sc15[384]f + bi15[384]f
#define OFF_W2PK 52224       // 6912: W2pk[9tap][48g][4j] packed i16x2 weights
#define OFF_A2   59136       // 1536: A2[48g][4j][2h] = s2/15
#define OFF_B2   60672       // 1536: B2[...] = 15*b2' + 0.5
#define OFF_BLOB3 62208      // 25088: w3 i8 frags [12ks][4nt][64lane][8j] + scale3[64] + bias3[64]
#define OFF_MAX  87296       // 12: uint-as-float max|w|
#define OFF_H1 1048576       // 12 blocks * BLKPB
#define OFF_H2 20316160      // 12 blocks * BLKPB

typedef int v4i __attribute__((ext_vector_type(4)));
typedef float f32x4 __attribute__((ext_vector_type(4)));
typedef short bf16x8 __attribute__((ext_vector_type(8)));

__device__ __forceinline__ short splitbf(float f, float& rem) {
  __hip_bfloat16 h = __float2bfloat16(f);
  rem = f - __bfloat162float(h);
  return __builtin_bit_cast(short, h);
}

__device__ __forceinline__ int pk_mad(unsigned int w, int a, int c) {
  int d;
  asm("v_pk_mad_i16 %0, %1, %2, %3" : "=v"(d) : "v"(w), "v"(a), "v"(c));
  return d;
}

// channel of (group g, pair j, half h) in the nibble-packed layout
__device__ __forceinline__ int ch_of(int g, int j, int h) {
  return 32 * (g >> 2) + 4 * (g & 3) + 16 * (j & 1) + ((j >> 1) & 1) + 2 * h;
}

// 48 blocks: max|w| per tensor (tanh applied later: max|tanh w| = tanh(max|w|))
__global__ __launch_bounds__(256) void prep_max(
    const float* __restrict__ w1, const float* __restrict__ w2,
    const float* __restrict__ w3, unsigned int* __restrict__ maxout) {
  int b = blockIdx.x >> 4;
  int sub = blockIdx.x & 15;
  const float* src = (b == 0) ? w1 : (b == 1) ? w2 : w3;
  int n = (b == 1) ? HID * 9 : HID * CIN;
  float m = 0.f;
  for (int i = sub * 256 + threadIdx.x; i < n; i += 4096)
    m = fmaxf(m, fabsf(src[i]));
  #pragma unroll
  for (int off = 32; off > 0; off >>= 1)
    m = fmaxf(m, __shfl_down(m, off, 64));
  __shared__ float red[4];
  if ((threadIdx.x & 63) == 0) red[threadIdx.x >> 6] = m;
  __syncthreads();
  if (threadIdx.x == 0) {
    m = fmaxf(fmaxf(red[0], red[1]), fmaxf(red[2], red[3]));
    atomicMax(maxout + b, __float_as_uint(m));
  }
}

// builds all folded/permuted weight blobs. 52544 ids -> 206 blocks.
__global__ __launch_bounds__(256) void prep_quant(
    const float* __restrict__ w1, const float* __restrict__ w2,
    const float* __restrict__ w3,
    const float* __restrict__ g1, const float* __restrict__ b1,
    const float* __restrict__ m1, const float* __restrict__ v1,
    const float* __restrict__ g2, const float* __restrict__ b2,
    const float* __restrict__ m2, const float* __restrict__ v2,
    const float* __restrict__ g3, const float* __restrict__ b3,
    const float* __restrict__ m3, const float* __restrict__ v3,
    char* __restrict__ ws) {
  const float* maxv = (const float*)(ws + OFF_MAX);
  int idx = blockIdx.x * 256 + threadIdx.x;
  if (idx < 24576) {                      // W1frag bf16 (exact odd ints -15..15)
    float mm = tanhf(maxv[0]);
    int e = idx & 7, lane = (idx >> 3) & 63, ks = (idx >> 9) & 1, mt = idx >> 10;
    int o = mt * 16 + (lane & 15);
    int k = ks * 32 + (lane >> 4) * 8 + e;
    float t = tanhf(w1[o * 64 + k]);
    int wi = 2 * (int)rintf((t / (2.f * mm) + 0.5f) * 15.f) - 15;
    float rr;
    ((short*)(ws + OFF_BLOB1))[idx] = splitbf((float)wi, rr);
  } else if (idx < 26304) {               // W2pk packed i16x2 integer weights
    float mm = tanhf(maxv[1]);
    int jj = idx - 24576;
    int tap = jj / 192, rem = jj - tap * 192;
    int g = rem >> 2, j = rem & 3;
    int clo = ch_of(g, j, 0), chi = ch_of(g, j, 1);
    int wlo = 2 * (int)rintf((tanhf(w2[clo * 9 + tap]) / (2.f * mm) + 0.5f) * 15.f) - 15;
    int whi = 2 * (int)rintf((tanhf(w2[chi * 9 + tap]) / (2.f * mm) + 0.5f) * 15.f) - 15;
    ((unsigned int*)(ws + OFF_W2PK))[jj] =
        ((unsigned int)(unsigned short)(short)wlo) |
        (((unsigned int)(unsigned short)(short)whi) << 16);
  } else if (idx < 26688) {               // A2 = s2/15
    int ii = idx - 26304;
    int g = ii >> 3, j = (ii >> 1) & 3, h = ii & 1;
    int c = ch_of(g, j, h);
    float s = g2[c] / sqrtf(v2[c] + EPS);
    ((float*)(ws + OFF_A2))[ii] = s * (1.f / 15.f);
  } else if (idx < 27072) {               // B2 = 15*b2' + 0.5
    int ii = idx - 26688;
    int g = ii >> 3, j = (ii >> 1) & 3, h = ii & 1;
    int c = ch_of(g, j, h);
    float s = g2[c] / sqrtf(v2[c] + EPS);
    ((float*)(ws + OFF_B2))[ii] = 15.f * (b2[c] - m2[c] * s) + 0.5f;
  } else if (idx < 27456) {               // sc15 = s1
    int o = idx - 27072;
    ((float*)(ws + OFF_BLOB1 + 49152))[o] = g1[o] / sqrtf(v1[o] + EPS);
  } else if (idx < 27840) {               // bi15 = 15*(b1 - m1*s1)
    int o = idx - 27456;
    float s = g1[o] / sqrtf(v1[o] + EPS);
    ((float*)(ws + OFF_BLOB1 + 50688))[o] = 15.f * (b1[o] - m1[o] * s);
  } else if (idx < 52416) {               // w3 i8 frags, nibble-permuted k
    float mm = tanhf(maxv[2]);
    int jj = idx - 27840;
    int j = jj & 7, lane = (jj >> 3) & 63, nt = (jj >> 9) & 3, ks = jj >> 11;
    int n = nt * 16 + (lane & 15);
    int quad = lane >> 4;
    int k = ks * 32 + ((j & 1) ? (16 + quad * 4 + (j >> 1)) : (quad * 4 + (j >> 1)));
    float t = tanhf(w3[n * 384 + k]);
    int wi = 2 * (int)rintf((t / (2.f * mm) + 0.5f) * 15.f) - 15;
    (ws + OFF_BLOB3)[jj] = (char)wi;
  } else if (idx < 52480) {               // scale3 = s3/225
    int n = idx - 52416;
    float s = g3[n] / sqrtf(v3[n] + EPS);
    *(float*)(ws + OFF_BLOB3 + 24576 + n * 4) = s * (1.f / 225.f);
  } else if (idx < 52544) {               // bias3
    int n = idx - 52480;
    float s = g3[n] / sqrtf(v3[n] + EPS);
    *(float*)(ws + OFF_BLOB3 + 24832 + n * 4) = b3[n] - m3[n] * s;
  }
}

// conv1 1x1 (64->384) via bf16 MFMA (x = hi+lo+lo2, exact int weights) + bn + relu
// + act_quant -> packed nibbles. grid 1568 blocks x 64 px; wave = 16 px.
__global__ __launch_bounds__(256) void k1(
    const float* __restrict__ x, const char* __restrict__ blob1,
    char* __restrict__ h1b) {
  __shared__ uint4 sBuf[3264];    // 49152B wfrags + 1536B sc15 + 1536B bi15
  int tid = threadIdx.x;
  {
    const uint4* src = (const uint4*)blob1;
    for (int i = tid; i < 3264; i += 256) sBuf[i] = src[i];
  }
  __syncthreads();
  const bf16x8* wf = (const bf16x8*)sBuf;
  const float* sSB = (const float*)(sBuf + 3072);   // [0..383]=sc15, [384..767]=bi15

  int wv = tid >> 6, lane = tid & 63;
  int quad = lane >> 4, m = lane & 15;
  size_t pixabs = (size_t)blockIdx.x * 64 + wv * 16 + m;
  int img = blockIdx.x / 49;
  int prem = (blockIdx.x - img * 49) * 64 + wv * 16 + m;
  const float* xb = x + (size_t)img * (CIN * HW) + prem;

  bf16x8 xh[2], xl[2], xq[2];
  #pragma unroll
  for (int ks = 0; ks < 2; ks++) {
    #pragma unroll
    for (int e = 0; e < 8; e++) {
      float f = xb[(size_t)(ks * 32 + quad * 8 + e) * HW];
      float r1, r2, r3;
      xh[ks][e] = splitbf(f, r1);
      xl[ks][e] = splitbf(r1, r2);
      xq[ks][e] = splitbf(r2, r3);
    }
  }

  #pragma unroll
  for (int half = 0; half < 2; half++) {
    f32x4 acc[12];
    #pragma unroll
    for (int i = 0; i < 12; i++) { f32x4 z = {0.f, 0.f, 0.f, 0.f}; acc[i] = z; }
    #pragma unroll
    for (int i = 0; i < 12; i++) {
      int mt = half * 12 + i;
      bf16x8 w0 = wf[(mt * 2 + 0) * 64 + lane];
      bf16x8 w1 = wf[(mt * 2 + 1) * 64 + lane];
      acc[i] = __builtin_amdgcn_mfma_f32_16x16x32_bf16(w0, xh[0], acc[i], 0, 0, 0);
      acc[i] = __builtin_amdgcn_mfma_f32_16x16x32_bf16(w1, xh[1], acc[i], 0, 0, 0);
      acc[i] = __builtin_amdgcn_mfma_f32_16x16x32_bf16(w0, xl[0], acc[i], 0, 0, 0);
      acc[i] = __builtin_amdgcn_mfma_f32_16x16x32_bf16(w1, xl[1], acc[i], 0, 0, 0);
      acc[i] = __builtin_amdgcn_mfma_f32_16x16x32_bf16(w0, xq[0], acc[i], 0, 0, 0);
      acc[i] = __builtin_amdgcn_mfma_f32_16x16x32_bf16(w1, xq[1], acc[i], 0, 0, 0);
    }
    #pragma unroll
    for (int l = 0; l < 6; l++) {
      int b = half * 6 + l;
      f32x4 ae = acc[2 * l], ao = acc[2 * l + 1];
      unsigned int pk = 0;
      #pragma unroll
      for (int r = 0; r < 4; r++) {
        int oe = 32 * b + quad * 4 + r;
        int oo = oe + 16;
        float fe = fminf(fmaxf(ae[r] * sSB[oe] + sSB[384 + oe], 0.f), 15.f);
        float fo = fminf(fmaxf(ao[r] * sSB[oo] + sSB[384 + oo], 0.f), 15.f);
        pk |= ((unsigned int)(int)rintf(fe)) << (8 * r);
        pk |= ((unsigned int)(int)rintf(fo)) << (8 * r + 4);
      }
      *(unsigned int*)(h1b + (size_t)b * BLKPB + pixabs * 16 + quad * 4) = pk;
    }
  }
}

// depthwise 3x3 + bn + relu + act_quant via packed i16 integer mads.
// grid (1568, 3): block = 16 g-groups x 16 quads (4 px each) = 64 px
__global__ __launch_bounds__(256) void k2(
    const unsigned int* __restrict__ h1q, const char* __restrict__ wsrc,
    unsigned int* __restrict__ h2q) {
  __shared__ unsigned int sbuf[2496];   // W2pk 1728 + A2 384 + B2 384
  int tid = threadIdx.x;
  for (int i = tid; i < 2496; i += 256) sbuf[i] = ((const unsigned int*)wsrc)[i];
  __syncthreads();
  const uint4* W4 = (const uint4*)sbuf;
  const float* Af = (const float*)(sbuf + 1728);
  const float* Bf = Af + 384;

  int g = blockIdx.y * 16 + (tid & 15);
  int qid = tid >> 4;
  int img = blockIdx.x / 49;
  int trem = blockIdx.x - img * 49;
  int px0 = trem * 64 + qid * 4;
  int h = px0 / 56;
  int w0 = px0 - h * 56;
  size_t base_u = (size_t)(g >> 2) * NPIXU4 + (g & 3);
  size_t imgrow = (size_t)img * HW;

  int acc[4][4];
  #pragma unroll
  for (int p = 0; p < 4; p++)
    #pragma unroll
    for (int j = 0; j < 4; j++) acc[p][j] = 0;

  #pragma unroll
  for (int dh = 0; dh < 3; dh++) {
    int hr = h + dh - 1;
    bool vrow = (unsigned)hr < 56u;
    const unsigned int* rp = h1q + base_u + (imgrow + (size_t)hr * 56) * 4;
    int P[6][4];
    #pragma unroll
    for (int c = 0; c < 6; c++) {
      int wc = w0 + c - 1;
      unsigned int u = 0;
      if (vrow && (unsigned)wc < 56u) u = rp[(size_t)wc * 4];
      P[c][0] = (int)(u & 0x000F000Fu);
      P[c][1] = (int)((u >> 4) & 0x000F000Fu);
      P[c][2] = (int)((u >> 8) & 0x000F000Fu);
      P[c][3] = (int)((u >> 12) & 0x000F000Fu);
    }
    #pragma unroll
    for (int cw = 0; cw < 3; cw++) {
      uint4 wvv = W4[(dh * 3 + cw) * 48 + g];
      #pragma unroll
      for (int p = 0; p < 4; p++) {
        acc[p][0] = pk_mad(wvv.x, P[p + cw][0], acc[p][0]);
        acc[p][1] = pk_mad(wvv.y, P[p + cw][1], acc[p][1]);
        acc[p][2] = pk_mad(wvv.z, P[p + cw][2], acc[p][2]);
        acc[p][3] = pk_mad(wvv.w, P[p + cw][3], acc[p][3]);
      }
    }
  }

  float Ar[8], Br[8];
  #pragma unroll
  for (int i = 0; i < 8; i++) { Ar[i] = Af[g * 8 + i]; Br[i] = Bf[g * 8 + i]; }

  #pragma unroll
  for (int p = 0; p < 4; p++) {
    unsigned int pk = 0;
    #pragma unroll
    for (int j = 0; j < 4; j++) {
      int a = acc[p][j];
      int lo = (a << 16) >> 16;
      int hi = a >> 16;
      float vl = fmaf((float)lo, Ar[2 * j], Br[2 * j]);
      float vh = fmaf((float)hi, Ar[2 * j + 1], Br[2 * j + 1]);
      unsigned int ql = (unsigned int)fmaxf(fminf(vl, 15.49f), 0.f);
      unsigned int qh = (unsigned int)fmaxf(fminf(vh, 15.49f), 0.f);
      pk |= ql << (4 * j);
      pk |= qh << (4 * j + 16);
    }
    h2q[base_u + (imgrow + (size_t)px0 + p) * 4] = pk;
  }
}

// conv3 1x1 (384->64) via i8 MFMA (exact) + bn + act_quant + residual -> fp32 out
__global__ __launch_bounds__(256) void InvertedBottleneck_conv_Q_13709535609694_kernel(
    const unsigned int* __restrict__ h2q, const char* __restrict__ blob,
    const float* __restrict__ x, float* __restrict__ out) {
  __shared__ long lds8[3136];   // 24576 B frags + 256 B scale3 + 256 B bias3
  int tid = threadIdx.x;
  {
    const long* src = (const long*)blob;
    #pragma unroll
    for (int i = 0; i < 13; i++) {
      int j = tid + i * 256;
      if (j < 3136) lds8[j] = src[j];
    }
  }
  __syncthreads();

  int wv = tid >> 6;
  int lane = tid & 63;
  int m = lane & 15;
  int quad = lane >> 4;
  int pixW = blockIdx.x * 64 + wv * 16;

  const unsigned int* aptr = h2q + (size_t)(pixW + m) * 4 + quad;
  unsigned int ua[12];
  #pragma unroll
  for (int ks = 0; ks < 12; ks++) ua[ks] = aptr[(size_t)ks * NPIXU4];

  v4i acc[4];
  #pragma unroll
  for (int nt = 0; nt < 4; nt++) { v4i z = {0,0,0,0}; acc[nt] = z; }

  #pragma unroll
  for (int ks = 0; ks < 12; ks++) {
    unsigned int u = ua[ks];
    unsigned int t = u & 0x0F0F0F0Fu;
    unsigned int s = (u >> 4) & 0x0F0F0F0Fu;
    unsigned int d0 = (t & 0xFFu) | ((s & 0xFFu) << 8) | ((t & 0xFF00u) << 8) | ((s & 0xFF00u) << 16);
    unsigned int d1 = ((t >> 16) & 0xFFu) | (((s >> 16) & 0xFFu) << 8) | ((t >> 24) << 16) | ((s >> 24) << 24);
    long aF = (long)(((unsigned long)d1 << 32) | (unsigned long)d0);
    #pragma unroll
    for (int nt = 0; nt < 4; nt++) {
      long bF = lds8[(ks * 4 + nt) * 64 + lane];
      acc[nt] = __builtin_amdgcn_mfma_i32_16x16x32_i8(aF, bF, acc[nt], 0, 0, 0);
    }
  }

  const float* scl = (const float*)(lds8 + 3072);
  int img = blockIdx.x / 49;
  int prem = (blockIdx.x - img * 49) * 64 + wv * 16 + quad * 4;

  #pragma unroll
  for (int nt = 0; nt < 4; nt++) {
    int n = nt * 16 + m;
    float sc = scl[n];
    float bi = scl[64 + n];
    size_t off = ((size_t)img * CIN + n) * HW + prem;
    const float4 xv = *(const float4*)(x + off);
    float4 ov;
    float v, a;
    v = (float)acc[nt][0] * sc + bi; a = fminf(fmaxf(v, 0.f), 1.f); ov.x = rintf(a * 15.f) * INV15 + xv.x;
    v = (float)acc[nt][1] * sc + bi; a = fminf(fmaxf(v, 0.f), 1.f); ov.y = rintf(a * 15.f) * INV15 + xv.y;
    v = (float)acc[nt][2] * sc + bi; a = fminf(fmaxf(v, 0.f), 1.f); ov.z = rintf(a * 15.f) * INV15 + xv.z;
    v = (float)acc[nt][3] * sc + bi; a = fminf(fmaxf(v, 0.f), 1.f); ov.w = rintf(a * 15.f) * INV15 + xv.w;
    *(float4*)(out + off) = ov;
  }
}

extern "C" void kernel_launch(void* const* d_in, const int* in_sizes, int n_in,
                              void* d_out, int out_size, void* d_ws, size_t ws_size,
                              hipStream_t stream) {
  const float* x  = (const float*)d_in[0];
  const float* w1 = (const float*)d_in[1];
  const float* w2 = (const float*)d_in[2];
  const float* w3 = (const float*)d_in[3];
  const float* g1 = (const float*)d_in[4];
  const float* b1 = (const float*)d_in[5];
  const float* m1 = (const float*)d_in[6];
  const float* v1 = (const float*)d_in[7];
  const float* g2 = (const float*)d_in[8];
  const float* b2 = (const float*)d_in[9];
  const float* m2 = (const float*)d_in[10];
  const float* v2 = (const float*)d_in[11];
  const float* g3 = (const float*)d_in[12];
  const float* b3 = (const float*)d_in[13];
  const float* m3 = (const float*)d_in[14];
  const float* v3 = (const float*)d_in[15];

  char* ws = (char*)d_ws;
  unsigned int* maxu = (unsigned int*)(ws + OFF_MAX);
  char* h1b = ws + OFF_H1;
  char* h2b = ws + OFF_H2;
  float* outp = (float*)d_out;

  hipMemsetAsync(maxu, 0, 12, stream);
  prep_max<<<dim3(48), dim3(256), 0, stream>>>(w1, w2, w3, maxu);
  prep_quant<<<dim3(206), dim3(256), 0, stream>>>(
      w1, w2, w3, g1, b1, m1, v1, g2, b2, m2, v2, g3, b3, m3, v3, ws);
  k1<<<dim3(1568), dim3(256), 0, stream>>>(x, ws + OFF_BLOB1, h1b);
  k2<<<dim3(1568, 3), dim3(256), 0, stream>>>(
      (const unsigned int*)h1b, ws + OFF_W2PK, (unsigned int*)h2b);
  InvertedBottleneck_conv_Q_13709535609694_kernel<<<dim3(1568), dim3(256), 0, stream>>>(
      (const unsigned int*)h2b, ws + OFF_BLOB3, x, outp);
}